// Round 2
// baseline (12692.303 us; speedup 1.0000x reference)
//
#include <hip/hip_runtime.h>
#include <hip/hip_bf16.h>

#define D 128
#define H 8
#define DH 16
#define FF 512

typedef __hip_bfloat16 bf16;

__device__ __forceinline__ float b2f(bf16 x) { return __bfloat162float(x); }

__device__ __forceinline__ unsigned short bfbits(float x) {
    bf16 h = __float2bfloat16(x);
    unsigned short s;
    __builtin_memcpy(&s, &h, 2);
    return s;
}

// decode 8 bf16 (as uint4) -> 8 f32
__device__ __forceinline__ void dec8(uint4 u, float* f) {
    f[0] = __uint_as_float(u.x << 16); f[1] = __uint_as_float(u.x & 0xffff0000u);
    f[2] = __uint_as_float(u.y << 16); f[3] = __uint_as_float(u.y & 0xffff0000u);
    f[4] = __uint_as_float(u.z << 16); f[5] = __uint_as_float(u.z & 0xffff0000u);
    f[6] = __uint_as_float(u.w << 16); f[7] = __uint_as_float(u.w & 0xffff0000u);
}

// ordered-uint encoding for float atomicMax (u=0 is below every encoding)
__device__ __forceinline__ unsigned enc_f32(float v) {
    unsigned b = __float_as_uint(v);
    return (b & 0x80000000u) ? ~b : (b | 0x80000000u);
}
__device__ __forceinline__ float dec_f32(unsigned u) {
    unsigned b = (u & 0x80000000u) ? (u & 0x7fffffffu) : ~u;
    return __uint_as_float(b);
}

// ---------------------------------------------------------------------------
// K1: q,k,v = feat @ W{q,k,v} + b   (f32 in, f32 accum, bf16 out to ws)
// grid: (ceil(N/64), 6)  y: 0,1->q cols 0-63/64-127; 2,3->k; 4,5->v
// ---------------------------------------------------------------------------
__global__ __launch_bounds__(256) void qkv_gemm(
    const float* __restrict__ feat,
    const float* __restrict__ Wq, const float* __restrict__ bq,
    const float* __restrict__ Wk, const float* __restrict__ bk,
    const float* __restrict__ Wv, const float* __restrict__ bv,
    bf16* __restrict__ q, bf16* __restrict__ k, bf16* __restrict__ v,
    int N)
{
    __shared__ float As[128][68];  // As[kk][r] (A transposed), pad 68 vs bank conflicts
    __shared__ float Bs[128][68];  // Bs[kk][c]

    const int tid = threadIdx.x;
    const int m0 = blockIdx.x * 64;
    const int which = blockIdx.y >> 1;
    const int col0 = (blockIdx.y & 1) * 64;
    const float* W    = which == 0 ? Wq : (which == 1 ? Wk : Wv);
    const float* bias = which == 0 ? bq : (which == 1 ? bk : bv);
    bf16* out         = which == 0 ? q  : (which == 1 ? k  : v);

    // stage A: 64 rows x 128 cols of feat -> As[kk][r]; 2048 float4 loads
    for (int c = tid; c < 2048; c += 256) {
        int r  = c >> 5;
        int k0 = (c & 31) * 4;
        float4 f = make_float4(0.f, 0.f, 0.f, 0.f);
        if (m0 + r < N) f = *(const float4*)(feat + (size_t)(m0 + r) * D + k0);
        As[k0 + 0][r] = f.x; As[k0 + 1][r] = f.y; As[k0 + 2][r] = f.z; As[k0 + 3][r] = f.w;
    }
    // stage B: W[kk][col0 + c] -> Bs[kk][c]; 64 cols = 16 float4 per kk
    for (int c = tid; c < 2048; c += 256) {
        int kk = c >> 4;
        int c0 = (c & 15) * 4;
        float4 f = *(const float4*)(W + (size_t)kk * D + col0 + c0);
        Bs[kk][c0 + 0] = f.x; Bs[kk][c0 + 1] = f.y; Bs[kk][c0 + 2] = f.z; Bs[kk][c0 + 3] = f.w;
    }
    __syncthreads();

    const int tr = tid >> 4, tc = tid & 15;
    const int r0 = tr * 4, c0 = tc * 4;
    float acc[4][4] = {};
    for (int kk = 0; kk < 128; kk++) {
        float4 a4 = *(const float4*)&As[kk][r0];
        float4 b4 = *(const float4*)&Bs[kk][c0];
        const float a[4] = {a4.x, a4.y, a4.z, a4.w};
        const float b[4] = {b4.x, b4.y, b4.z, b4.w};
        #pragma unroll
        for (int i = 0; i < 4; i++)
            #pragma unroll
            for (int j = 0; j < 4; j++)
                acc[i][j] += a[i] * b[j];
    }

    float bv4[4];
    #pragma unroll
    for (int j = 0; j < 4; j++) bv4[j] = bias[col0 + c0 + j];

    #pragma unroll
    for (int i = 0; i < 4; i++) {
        int r = m0 + r0 + i;
        if (r < N) {
            uint2 pk;
            pk.x = (unsigned)bfbits(acc[i][0] + bv4[0]) | ((unsigned)bfbits(acc[i][1] + bv4[1]) << 16);
            pk.y = (unsigned)bfbits(acc[i][2] + bv4[2]) | ((unsigned)bfbits(acc[i][3] + bv4[3]) << 16);
            *(uint2*)(out + (size_t)r * D + col0 + c0) = pk;
        }
    }
}

// ---------------------------------------------------------------------------
// K2: zero agg [N*D], emax_u [N*H], denom [N*H]
// ---------------------------------------------------------------------------
__global__ __launch_bounds__(256) void init_buf(
    float* __restrict__ agg, unsigned* __restrict__ emax_u, float* __restrict__ denom,
    int ND, int NH)
{
    int idx = blockIdx.x * 256 + threadIdx.x;
    if (idx < ND) agg[idx] = 0.f;
    if (idx < NH) { emax_u[idx] = 0u; denom[idx] = 0.f; }
}

// ---------------------------------------------------------------------------
// K3: per (edge, head): s = <k[src],q[dst]>/sqrt(D); atomicMax emax
// ---------------------------------------------------------------------------
__global__ __launch_bounds__(256) void edge_scores(
    const bf16* __restrict__ kbuf, const bf16* __restrict__ qbuf,
    const int* __restrict__ src, const int* __restrict__ dst,
    float* __restrict__ s, unsigned* __restrict__ emax_u, int EH)
{
    int idx = blockIdx.x * 256 + threadIdx.x;
    if (idx >= EH) return;
    int e = idx >> 3, h = idx & 7;
    int sn = src[e], dn = dst[e];
    const bf16* kp = kbuf + (size_t)sn * D + h * DH;
    const bf16* qp = qbuf + (size_t)dn * D + h * DH;
    float kf[16], qf[16];
    dec8(*(const uint4*)kp, kf);
    dec8(*(const uint4*)(kp + 8), kf + 8);
    dec8(*(const uint4*)qp, qf);
    dec8(*(const uint4*)(qp + 8), qf + 8);
    float acc = 0.f;
    #pragma unroll
    for (int i = 0; i < 16; i++) acc += kf[i] * qf[i];
    float val = acc * 0.08838834764831845f;  // 1/sqrt(128)
    s[idx] = val;
    atomicMax(&emax_u[dn * H + h], enc_f32(val));
}

// ---------------------------------------------------------------------------
// K4: per (edge, head): ex = exp(s - max); denom += ex; agg[dst] += ex * v[src]
// ---------------------------------------------------------------------------
__global__ __launch_bounds__(256) void edge_agg(
    const bf16* __restrict__ vbuf,
    const int* __restrict__ src, const int* __restrict__ dst,
    const float* __restrict__ s, const unsigned* __restrict__ emax_u,
    float* __restrict__ denom, float* __restrict__ agg, int EH)
{
    int idx = blockIdx.x * 256 + threadIdx.x;
    if (idx >= EH) return;
    int e = idx >> 3, h = idx & 7;
    int sn = src[e], dn = dst[e];
    float m = dec_f32(emax_u[dn * H + h]);
    float ex = __expf(s[idx] - m);
    atomicAdd(&denom[dn * H + h], ex);
    const bf16* vp = vbuf + (size_t)sn * D + h * DH;
    float vf[16];
    dec8(*(const uint4*)vp, vf);
    dec8(*(const uint4*)(vp + 8), vf + 8);
    float* ag = agg + (size_t)dn * D + h * DH;
    #pragma unroll
    for (int i = 0; i < 16; i++) atomicAdd(&ag[i], ex * vf[i]);
}

// ---------------------------------------------------------------------------
// K5: per node: rst = agg/denom + feat; LN1 -> rst_ln (bf16)
// grid: N blocks, 128 threads
// ---------------------------------------------------------------------------
__global__ __launch_bounds__(128) void norm_ln(
    const float* __restrict__ agg, const float* __restrict__ denom,
    const float* __restrict__ feat,
    const float* __restrict__ g, const float* __restrict__ b,
    bf16* __restrict__ rst_ln, int N)
{
    __shared__ float red[4];
    int n = blockIdx.x;
    int j = threadIdx.x;
    int h = j >> 4;
    float den = denom[n * H + h];
    float val = agg[(size_t)n * D + j];
    val = (den != 0.f) ? val / den : 0.f;
    val += feat[(size_t)n * D + j];

    float s1 = val, s2 = val * val;
    #pragma unroll
    for (int o = 32; o > 0; o >>= 1) {
        s1 += __shfl_xor(s1, o);
        s2 += __shfl_xor(s2, o);
    }
    int w = j >> 6;
    if ((j & 63) == 0) { red[w * 2] = s1; red[w * 2 + 1] = s2; }
    __syncthreads();
    float t1 = red[0] + red[2], t2 = red[1] + red[3];
    float mu = t1 * (1.f / 128.f);
    float var = t2 * (1.f / 128.f) - mu * mu;
    float y = (val - mu) * rsqrtf(var + 1e-5f) * g[j] + b[j];
    rst_ln[(size_t)n * D + j] = __float2bfloat16(y);
}

// ---------------------------------------------------------------------------
// K6: fused FFN + residual + LN2 -> out (f32)
// 16 nodes per block, 256 threads = 4 waves; wave w owns rows 4w..4w+3.
// GEMM1 (K=128): lane l owns cols l*8..l*8+7 of h.  h kept in LDS.
// GEMM2 (K=512): lane l owns cols 2l,2l+1 of out.  Row fully inside one wave
//                -> LN via wave shuffles.
// ---------------------------------------------------------------------------
__global__ __launch_bounds__(256) void ffn_fused(
    const bf16* __restrict__ rst_ln,
    const float* __restrict__ W1, const float* __restrict__ b1,
    const float* __restrict__ alpha,
    const float* __restrict__ W2, const float* __restrict__ b2,
    const float* __restrict__ g, const float* __restrict__ bln,
    float* __restrict__ out, int N)
{
    __shared__ float xs[16][132];
    __shared__ float hs[16][520];
    const int tid = threadIdx.x;
    const int n0 = blockIdx.x * 16;

    {
        int r = tid >> 4, c0 = (tid & 15) * 8;
        float f[8];
        if (n0 + r < N) {
            uint4 u = *(const uint4*)(rst_ln + (size_t)(n0 + r) * D + c0);
            dec8(u, f);
        } else {
            #pragma unroll
            for (int i = 0; i < 8; i++) f[i] = 0.f;
        }
        #pragma unroll
        for (int i = 0; i < 8; i++) xs[r][c0 + i] = f[i];
    }
    __syncthreads();

    const int w = tid >> 6, l = tid & 63;
    const int r0 = w * 4;

    // GEMM1: h = PReLU(x @ W1 + b1)
    float acc[4][8] = {};
    const float* w1p = W1 + l * 8;
    for (int kk = 0; kk < 128; kk++) {
        float4 u0 = *(const float4*)(w1p + (size_t)kk * FF);
        float4 u1 = *(const float4*)(w1p + (size_t)kk * FF + 4);
        const float wv[8] = {u0.x, u0.y, u0.z, u0.w, u1.x, u1.y, u1.z, u1.w};
        #pragma unroll
        for (int i = 0; i < 4; i++) {
            float a = xs[r0 + i][kk];
            #pragma unroll
            for (int jj = 0; jj < 8; jj++) acc[i][jj] += a * wv[jj];
        }
    }
    {
        float bv[8], av[8];
        #pragma unroll
        for (int jj = 0; jj < 8; jj++) { bv[jj] = b1[l * 8 + jj]; av[jj] = alpha[l * 8 + jj]; }
        #pragma unroll
        for (int i = 0; i < 4; i++) {
            #pragma unroll
            for (int jj = 0; jj < 8; jj++) {
                float hv = acc[i][jj] + bv[jj];
                hs[r0 + i][l * 8 + jj] = hv > 0.f ? hv : av[jj] * hv;
            }
        }
    }
    __syncthreads();

    // GEMM2: ffn = h @ W2 + b2
    float acc2[4][2] = {};
    const float* w2p = W2 + 2 * l;
    #pragma unroll 4
    for (int kk = 0; kk < 512; kk++) {
        float2 u = *(const float2*)(w2p + (size_t)kk * D);
        #pragma unroll
        for (int i = 0; i < 4; i++) {
            float hh = hs[r0 + i][kk];
            acc2[i][0] += hh * u.x;
            acc2[i][1] += hh * u.y;
        }
    }

    const float bb0 = b2[2 * l],  bb1 = b2[2 * l + 1];
    const float g0 = g[2 * l],    g1 = g[2 * l + 1];
    const float bl0 = bln[2 * l], bl1 = bln[2 * l + 1];

    #pragma unroll
    for (int i = 0; i < 4; i++) {
        float v0 = acc2[i][0] + bb0 + xs[r0 + i][2 * l];
        float v1 = acc2[i][1] + bb1 + xs[r0 + i][2 * l + 1];
        float s1 = v0 + v1, s2 = v0 * v0 + v1 * v1;
        #pragma unroll
        for (int o = 32; o > 0; o >>= 1) {
            s1 += __shfl_xor(s1, o);
            s2 += __shfl_xor(s2, o);
        }
        float mu = s1 * (1.f / 128.f);
        float var = s2 * (1.f / 128.f) - mu * mu;
        float rs = rsqrtf(var + 1e-5f);
        int r = n0 + r0 + i;
        if (r < N) {
            float2 o2;
            o2.x = (v0 - mu) * rs * g0 + bl0;
            o2.y = (v1 - mu) * rs * g1 + bl1;
            *(float2*)(out + (size_t)r * D + 2 * l) = o2;
        }
    }
}

// ---------------------------------------------------------------------------
extern "C" void kernel_launch(void* const* d_in, const int* in_sizes, int n_in,
                              void* d_out, int out_size, void* d_ws, size_t ws_size,
                              hipStream_t stream) {
    const float* feat = (const float*)d_in[0];
    const int*   src  = (const int*)d_in[1];
    const int*   dst  = (const int*)d_in[2];
    const float* Wq   = (const float*)d_in[3];
    const float* bq   = (const float*)d_in[4];
    const float* Wk   = (const float*)d_in[5];
    const float* bk   = (const float*)d_in[6];
    const float* Wv   = (const float*)d_in[7];
    const float* bv   = (const float*)d_in[8];
    const float* ln_g = (const float*)d_in[9];
    const float* ln_b = (const float*)d_in[10];
    const float* W1   = (const float*)d_in[11];
    const float* b1   = (const float*)d_in[12];
    const float* alp  = (const float*)d_in[13];
    const float* W2   = (const float*)d_in[14];
    const float* b2   = (const float*)d_in[15];
    float* out = (float*)d_out;

    const int N = in_sizes[0] / D;
    const int E = in_sizes[1];

    char* p = (char*)d_ws;
    auto take = [&](size_t bytes) { char* r = p; p += (bytes + 255) & ~(size_t)255; return r; };
    bf16*     qb    = (bf16*)take((size_t)N * D * 2);
    bf16*     kb    = (bf16*)take((size_t)N * D * 2);
    bf16*     vb    = (bf16*)take((size_t)N * D * 2);
    bf16*     rstln = (bf16*)take((size_t)N * D * 2);
    float*    sbuf  = (float*)take((size_t)E * H * 4);
    unsigned* emax  = (unsigned*)take((size_t)N * H * 4);
    float*    denom = (float*)take((size_t)N * H * 4);
    float*    agg   = (float*)take((size_t)N * D * 4);

    qkv_gemm<<<dim3((N + 63) / 64, 6), 256, 0, stream>>>(
        feat, Wq, bq, Wk, bk, Wv, bv, qb, kb, vb, N);

    const int ND = N * D, NH = N * H;
    init_buf<<<(ND + 255) / 256, 256, 0, stream>>>(agg, emax, denom, ND, NH);

    const int EH = E * H;
    edge_scores<<<(EH + 255) / 256, 256, 0, stream>>>(kb, qb, src, dst, sbuf, emax, EH);
    edge_agg<<<(EH + 255) / 256, 256, 0, stream>>>(vb, src, dst, sbuf, emax, denom, agg, EH);

    norm_ln<<<N, 128, 0, stream>>>(agg, denom, feat, ln_g, ln_b, rstln, N);

    ffn_fused<<<(N + 15) / 16, 256, 0, stream>>>(
        rstln, W1, b1, alp, W2, b2, ln_g, ln_b, out, N);
}

// Round 3
// 1213.747 us; speedup vs baseline: 10.4571x; 10.4571x over previous
//
#include <hip/hip_runtime.h>
#include <hip/hip_bf16.h>

#define D 128
#define H 8
#define DH 16
#define FF 512

typedef __hip_bfloat16 bf16;

__device__ __forceinline__ unsigned short bfbits(float x) {
    bf16 h = __float2bfloat16(x);
    unsigned short s;
    __builtin_memcpy(&s, &h, 2);
    return s;
}

// decode 8 bf16 (as uint4) -> 8 f32
__device__ __forceinline__ void dec8(uint4 u, float* f) {
    f[0] = __uint_as_float(u.x << 16); f[1] = __uint_as_float(u.x & 0xffff0000u);
    f[2] = __uint_as_float(u.y << 16); f[3] = __uint_as_float(u.y & 0xffff0000u);
    f[4] = __uint_as_float(u.z << 16); f[5] = __uint_as_float(u.z & 0xffff0000u);
    f[6] = __uint_as_float(u.w << 16); f[7] = __uint_as_float(u.w & 0xffff0000u);
}

// ---------------------------------------------------------------------------
// K1: q,k,v = feat @ W{q,k,v} + b   (f32 in, f32 accum, bf16 out to ws)
// ---------------------------------------------------------------------------
__global__ __launch_bounds__(256) void qkv_gemm(
    const float* __restrict__ feat,
    const float* __restrict__ Wq, const float* __restrict__ bq,
    const float* __restrict__ Wk, const float* __restrict__ bk,
    const float* __restrict__ Wv, const float* __restrict__ bv,
    bf16* __restrict__ q, bf16* __restrict__ k, bf16* __restrict__ v,
    int N)
{
    __shared__ float As[128][68];
    __shared__ float Bs[128][68];

    const int tid = threadIdx.x;
    const int m0 = blockIdx.x * 64;
    const int which = blockIdx.y >> 1;
    const int col0 = (blockIdx.y & 1) * 64;
    const float* W    = which == 0 ? Wq : (which == 1 ? Wk : Wv);
    const float* bias = which == 0 ? bq : (which == 1 ? bk : bv);
    bf16* out         = which == 0 ? q  : (which == 1 ? k  : v);

    for (int c = tid; c < 2048; c += 256) {
        int r  = c >> 5;
        int k0 = (c & 31) * 4;
        float4 f = make_float4(0.f, 0.f, 0.f, 0.f);
        if (m0 + r < N) f = *(const float4*)(feat + (size_t)(m0 + r) * D + k0);
        As[k0 + 0][r] = f.x; As[k0 + 1][r] = f.y; As[k0 + 2][r] = f.z; As[k0 + 3][r] = f.w;
    }
    for (int c = tid; c < 2048; c += 256) {
        int kk = c >> 4;
        int c0 = (c & 15) * 4;
        float4 f = *(const float4*)(W + (size_t)kk * D + col0 + c0);
        Bs[kk][c0 + 0] = f.x; Bs[kk][c0 + 1] = f.y; Bs[kk][c0 + 2] = f.z; Bs[kk][c0 + 3] = f.w;
    }
    __syncthreads();

    const int tr = tid >> 4, tc = tid & 15;
    const int r0 = tr * 4, c0 = tc * 4;
    float acc[4][4] = {};
    for (int kk = 0; kk < 128; kk++) {
        float4 a4 = *(const float4*)&As[kk][r0];
        float4 b4 = *(const float4*)&Bs[kk][c0];
        const float a[4] = {a4.x, a4.y, a4.z, a4.w};
        const float b[4] = {b4.x, b4.y, b4.z, b4.w};
        #pragma unroll
        for (int i = 0; i < 4; i++)
            #pragma unroll
            for (int j = 0; j < 4; j++)
                acc[i][j] += a[i] * b[j];
    }

    float bv4[4];
    #pragma unroll
    for (int j = 0; j < 4; j++) bv4[j] = bias[col0 + c0 + j];

    #pragma unroll
    for (int i = 0; i < 4; i++) {
        int r = m0 + r0 + i;
        if (r < N) {
            uint2 pk;
            pk.x = (unsigned)bfbits(acc[i][0] + bv4[0]) | ((unsigned)bfbits(acc[i][1] + bv4[1]) << 16);
            pk.y = (unsigned)bfbits(acc[i][2] + bv4[2]) | ((unsigned)bfbits(acc[i][3] + bv4[3]) << 16);
            *(uint2*)(out + (size_t)r * D + col0 + c0) = pk;
        }
    }
}

// ---------------------------------------------------------------------------
// CSR build: histogram -> scan (3 small kernels) -> scatter
// ---------------------------------------------------------------------------
__global__ __launch_bounds__(256) void hist_kernel(
    const int* __restrict__ dst, int* __restrict__ deg, int E)
{
    int i = blockIdx.x * 256 + threadIdx.x;
    if (i < E) atomicAdd(&deg[dst[i]], 1);
}

__global__ __launch_bounds__(256) void scan_bsum(
    const int* __restrict__ deg, int* __restrict__ bsum, int N)
{
    int base = blockIdx.x * 1024;
    int t = threadIdx.x;
    int s = 0;
    #pragma unroll
    for (int j = 0; j < 4; j++) {
        int i = base + t + 256 * j;
        if (i < N) s += deg[i];
    }
    #pragma unroll
    for (int o = 1; o < 64; o <<= 1) s += __shfl_xor(s, o);
    __shared__ int ws[4];
    if ((t & 63) == 0) ws[t >> 6] = s;
    __syncthreads();
    if (t == 0) bsum[blockIdx.x] = ws[0] + ws[1] + ws[2] + ws[3];
}

__global__ void scan_bofs(const int* __restrict__ bsum, int* __restrict__ bofs, int nb)
{
    if (threadIdx.x == 0) {
        int run = 0;
        for (int i = 0; i < nb; i++) { bofs[i] = run; run += bsum[i]; }
    }
}

__global__ __launch_bounds__(256) void scan_write(
    const int* __restrict__ deg, const int* __restrict__ bofs,
    int* __restrict__ row_off, int* __restrict__ cur, int N)
{
    int t = threadIdx.x;
    int base = blockIdx.x * 1024 + t * 4;
    int d[4]; int tot = 0;
    #pragma unroll
    for (int j = 0; j < 4; j++) {
        int i = base + j;
        d[j] = (i < N) ? deg[i] : 0;
        tot += d[j];
    }
    int incl = tot;
    int lane = t & 63;
    #pragma unroll
    for (int o = 1; o < 64; o <<= 1) {
        int nv = __shfl_up(incl, o);
        if (lane >= o) incl += nv;
    }
    __shared__ int ws[4];
    if (lane == 63) ws[t >> 6] = incl;
    __syncthreads();
    int w = t >> 6;
    int woff = 0;
    #pragma unroll
    for (int kk = 0; kk < 4; kk++) if (kk < w) woff += ws[kk];
    int run = bofs[blockIdx.x] + woff + incl - tot;
    #pragma unroll
    for (int j = 0; j < 4; j++) {
        int i = base + j;
        if (i < N) { row_off[i] = run; cur[i] = run; }
        run += d[j];
    }
}

__global__ __launch_bounds__(256) void scatter_kernel(
    const int* __restrict__ src, const int* __restrict__ dst,
    int* __restrict__ cur, int* __restrict__ csr, int E)
{
    int i = blockIdx.x * 256 + threadIdx.x;
    if (i < E) {
        int d = dst[i];
        int pos = atomicAdd(&cur[d], 1);
        csr[pos] = src[i];
    }
}

// ---------------------------------------------------------------------------
// K-node: fused per-node scores + online softmax + V-agg + residual + LN1.
// One wave per node; 4 nodes per 256-thread block. No atomics, no barriers.
// Lane roles: score phase (e_local=l>>3, h=l&7); accum phase owns dims 2l,2l+1
// (head ha=l>>3). Per-head state replicated in the 8 lanes of each h-group.
// ---------------------------------------------------------------------------
__global__ __launch_bounds__(256) void node_agg(
    const bf16* __restrict__ kb, const bf16* __restrict__ qb, const bf16* __restrict__ vb,
    const int* __restrict__ csr, const int* __restrict__ row_off, const int* __restrict__ deg,
    const float* __restrict__ feat, const float* __restrict__ g, const float* __restrict__ b,
    bf16* __restrict__ rst_ln, int N)
{
    __shared__ float qs[4][128];
    const int t = threadIdx.x;
    const int w = t >> 6, l = t & 63;
    const int n = blockIdx.x * 4 + w;
    if (n >= N) return;  // wave-uniform; no __syncthreads in this kernel

    // stage this node's q row into LDS as f32
    unsigned qu = *(const unsigned*)(qb + (size_t)n * D + 2 * l);
    qs[w][2 * l]     = __uint_as_float(qu << 16);
    qs[w][2 * l + 1] = __uint_as_float(qu & 0xffff0000u);

    const int rs = row_off[n], dn = deg[n];
    const int el = l >> 3, h = l & 7, ha = l >> 3;

    float m = -3.0e38f, lsum = 0.f, acc0 = 0.f, acc1 = 0.f;

    for (int base = 0; base < dn; base += 8) {
        int ei = base + el;
        bool valid = ei < dn;
        int sn = csr[rs + (valid ? ei : 0)];

        // score for (edge el, head h)
        const uint4* kp = (const uint4*)(kb + (size_t)sn * D + h * DH);
        uint4 k0 = kp[0], k1 = kp[1];
        float kf[16];
        dec8(k0, kf); dec8(k1, kf + 8);
        const float* qp = &qs[w][h * DH];
        float s = 0.f;
        #pragma unroll
        for (int i = 0; i < 16; i++) s += kf[i] * qp[i];
        s *= 0.08838834764831845f;  // 1/sqrt(128)
        if (!valid) s = -3.0e38f;

        // per-head chunk max (reduce over e: lanes differing in bits 3..5)
        float cmax = s;
        cmax = fmaxf(cmax, __shfl_xor(cmax, 8));
        cmax = fmaxf(cmax, __shfl_xor(cmax, 16));
        cmax = fmaxf(cmax, __shfl_xor(cmax, 32));
        float m_new = fmaxf(m, cmax);
        float alphaH = __expf(m - m_new);
        float wgt = __expf(s - m_new);
        float wsum = wgt;
        wsum += __shfl_xor(wsum, 8);
        wsum += __shfl_xor(wsum, 16);
        wsum += __shfl_xor(wsum, 32);
        lsum = lsum * alphaH + wsum;
        m = m_new;

        float alphaA = __shfl(alphaH, ha);  // alpha for accumulation head

        // weighted V accumulation: 8 independent coalesced row gathers
        float na0 = 0.f, na1 = 0.f;
        #pragma unroll
        for (int e = 0; e < 8; e++) {
            int sne = __shfl(sn, e * 8);
            unsigned vu = *(const unsigned*)(vb + (size_t)sne * D + 2 * l);
            float wv = __shfl(wgt, e * 8 + ha);
            na0 += wv * __uint_as_float(vu << 16);
            na1 += wv * __uint_as_float(vu & 0xffff0000u);
        }
        acc0 = acc0 * alphaA + na0;
        acc1 = acc1 * alphaA + na1;
    }

    float den = __shfl(lsum, ha);
    float v0 = (den > 0.f) ? acc0 / den : 0.f;
    float v1 = (den > 0.f) ? acc1 / den : 0.f;

    float2 fv = *(const float2*)(feat + (size_t)n * D + 2 * l);
    v0 += fv.x; v1 += fv.y;

    // LayerNorm over 128 dims (64 lanes x 2)
    float s1 = v0 + v1, s2 = v0 * v0 + v1 * v1;
    #pragma unroll
    for (int o = 1; o < 64; o <<= 1) {
        s1 += __shfl_xor(s1, o);
        s2 += __shfl_xor(s2, o);
    }
    float mu = s1 * (1.f / 128.f);
    float var = s2 * (1.f / 128.f) - mu * mu;
    float rsq = rsqrtf(var + 1e-5f);
    float y0 = (v0 - mu) * rsq * g[2 * l]     + b[2 * l];
    float y1 = (v1 - mu) * rsq * g[2 * l + 1] + b[2 * l + 1];
    unsigned pk = (unsigned)bfbits(y0) | ((unsigned)bfbits(y1) << 16);
    *(unsigned*)(rst_ln + (size_t)n * D + 2 * l) = pk;
}

// ---------------------------------------------------------------------------
// K6: fused FFN + residual + LN2 -> out (f32)
// ---------------------------------------------------------------------------
__global__ __launch_bounds__(256) void ffn_fused(
    const bf16* __restrict__ rst_ln,
    const float* __restrict__ W1, const float* __restrict__ b1,
    const float* __restrict__ alpha,
    const float* __restrict__ W2, const float* __restrict__ b2,
    const float* __restrict__ g, const float* __restrict__ bln,
    float* __restrict__ out, int N)
{
    __shared__ float xs[16][132];
    __shared__ float hs[16][520];
    const int tid = threadIdx.x;
    const int n0 = blockIdx.x * 16;

    {
        int r = tid >> 4, c0 = (tid & 15) * 8;
        float f[8];
        if (n0 + r < N) {
            uint4 u = *(const uint4*)(rst_ln + (size_t)(n0 + r) * D + c0);
            dec8(u, f);
        } else {
            #pragma unroll
            for (int i = 0; i < 8; i++) f[i] = 0.f;
        }
        #pragma unroll
        for (int i = 0; i < 8; i++) xs[r][c0 + i] = f[i];
    }
    __syncthreads();

    const int w = tid >> 6, l = tid & 63;
    const int r0 = w * 4;

    float acc[4][8] = {};
    const float* w1p = W1 + l * 8;
    for (int kk = 0; kk < 128; kk++) {
        float4 u0 = *(const float4*)(w1p + (size_t)kk * FF);
        float4 u1 = *(const float4*)(w1p + (size_t)kk * FF + 4);
        const float wv[8] = {u0.x, u0.y, u0.z, u0.w, u1.x, u1.y, u1.z, u1.w};
        #pragma unroll
        for (int i = 0; i < 4; i++) {
            float a = xs[r0 + i][kk];
            #pragma unroll
            for (int jj = 0; jj < 8; jj++) acc[i][jj] += a * wv[jj];
        }
    }
    {
        float bv[8], av[8];
        #pragma unroll
        for (int jj = 0; jj < 8; jj++) { bv[jj] = b1[l * 8 + jj]; av[jj] = alpha[l * 8 + jj]; }
        #pragma unroll
        for (int i = 0; i < 4; i++) {
            #pragma unroll
            for (int jj = 0; jj < 8; jj++) {
                float hv = acc[i][jj] + bv[jj];
                hs[r0 + i][l * 8 + jj] = hv > 0.f ? hv : av[jj] * hv;
            }
        }
    }
    __syncthreads();

    float acc2[4][2] = {};
    const float* w2p = W2 + 2 * l;
    #pragma unroll 4
    for (int kk = 0; kk < 512; kk++) {
        float2 u = *(const float2*)(w2p + (size_t)kk * D);
        #pragma unroll
        for (int i = 0; i < 4; i++) {
            float hh = hs[r0 + i][kk];
            acc2[i][0] += hh * u.x;
            acc2[i][1] += hh * u.y;
        }
    }

    const float bb0 = b2[2 * l],  bb1 = b2[2 * l + 1];
    const float g0 = g[2 * l],    g1 = g[2 * l + 1];
    const float bl0 = bln[2 * l], bl1 = bln[2 * l + 1];

    #pragma unroll
    for (int i = 0; i < 4; i++) {
        float v0 = acc2[i][0] + bb0 + xs[r0 + i][2 * l];
        float v1 = acc2[i][1] + bb1 + xs[r0 + i][2 * l + 1];
        float s1 = v0 + v1, s2 = v0 * v0 + v1 * v1;
        #pragma unroll
        for (int o = 32; o > 0; o >>= 1) {
            s1 += __shfl_xor(s1, o);
            s2 += __shfl_xor(s2, o);
        }
        float mu = s1 * (1.f / 128.f);
        float var = s2 * (1.f / 128.f) - mu * mu;
        float rs = rsqrtf(var + 1e-5f);
        int r = n0 + r0 + i;
        if (r < N) {
            float2 o2;
            o2.x = (v0 - mu) * rs * g0 + bl0;
            o2.y = (v1 - mu) * rs * g1 + bl1;
            *(float2*)(out + (size_t)r * D + 2 * l) = o2;
        }
    }
}

// ---------------------------------------------------------------------------
extern "C" void kernel_launch(void* const* d_in, const int* in_sizes, int n_in,
                              void* d_out, int out_size, void* d_ws, size_t ws_size,
                              hipStream_t stream) {
    const float* feat = (const float*)d_in[0];
    const int*   src  = (const int*)d_in[1];
    const int*   dst  = (const int*)d_in[2];
    const float* Wq   = (const float*)d_in[3];
    const float* bq   = (const float*)d_in[4];
    const float* Wk   = (const float*)d_in[5];
    const float* bk   = (const float*)d_in[6];
    const float* Wv   = (const float*)d_in[7];
    const float* bv   = (const float*)d_in[8];
    const float* ln_g = (const float*)d_in[9];
    const float* ln_b = (const float*)d_in[10];
    const float* W1   = (const float*)d_in[11];
    const float* b1   = (const float*)d_in[12];
    const float* alp  = (const float*)d_in[13];
    const float* W2   = (const float*)d_in[14];
    const float* b2   = (const float*)d_in[15];
    float* out = (float*)d_out;

    const int N = in_sizes[0] / D;
    const int E = in_sizes[1];
    const int nb = (N + 1023) / 1024;

    char* p = (char*)d_ws;
    auto take = [&](size_t bytes) { char* r = p; p += (bytes + 255) & ~(size_t)255; return r; };
    bf16* qb    = (bf16*)take((size_t)N * D * 2);
    bf16* kb    = (bf16*)take((size_t)N * D * 2);
    bf16* vb    = (bf16*)take((size_t)N * D * 2);
    bf16* rstln = (bf16*)take((size_t)N * D * 2);
    int*  degb  = (int*)take((size_t)N * 4);
    int*  rowof = (int*)take((size_t)N * 4);
    int*  curb  = (int*)take((size_t)N * 4);
    int*  csr   = (int*)take((size_t)E * 4);
    int*  bsum  = (int*)take((size_t)nb * 4);
    int*  bofs  = (int*)take((size_t)nb * 4);

    qkv_gemm<<<dim3((N + 63) / 64, 6), 256, 0, stream>>>(
        feat, Wq, bq, Wk, bk, Wv, bv, qb, kb, vb, N);

    hipMemsetAsync(degb, 0, (size_t)N * 4, stream);
    hist_kernel<<<(E + 255) / 256, 256, 0, stream>>>(dst, degb, E);
    scan_bsum<<<nb, 256, 0, stream>>>(degb, bsum, N);
    scan_bofs<<<1, 64, 0, stream>>>(bsum, bofs, nb);
    scan_write<<<nb, 256, 0, stream>>>(degb, bofs, rowof, curb, N);
    scatter_kernel<<<(E + 255) / 256, 256, 0, stream>>>(src, dst, curb, csr, E);

    node_agg<<<(N + 3) / 4, 256, 0, stream>>>(
        kb, qb, vb, csr, rowof, degb, feat, ln_g, ln_b, rstln, N);

    ffn_fused<<<(N + 15) / 16, 256, 0, stream>>>(
        rstln, W1, b1, alp, W2, b2, ln_g, ln_b, out, N);
}